// Round 6
// baseline (239.444 us; speedup 1.0000x reference)
//
#include <hip/hip_runtime.h>
#include <math.h>
#include <stdint.h>

// Problem: M=131072 rows, N=4000 verts, D=16. 4000 = 250 exact 16-col tiles.
#define M_ROWS   131072
#define N_VERTS  4000
#define D_DIM    16
#define N_TILES  250
#define TILE_B   2048          // per tile: B1 (64 lanes x 16B) + B2 (same)

// Scores biased +128 -> provably positive (score >= -||x||^2, chi^2_16) ->
// positive-float bits monotone as u32 -> min_u32 = fused best+argmin on
// keys = (score_bits & ~0xFF) | tile.
#define SCORE_BIAS 128.0f
// Error budget: key truncation <= 7.8e-3 (scores+bias < 512), arithmetic
// (dropped al*yl <= 5e-4, ysq split <= 7e-4, fp32 accum ~2e-4) <= 1.5e-3.
// TIE_EPS = 0.025 >= truncation + 2x arith with >2x margin.
#define TIE_EPS 0.025f

// d_ws layout (bytes):
//   [0      .. 524288)  yfrag : N_TILES x 2048 B (B1 | B2 fragments)
//   [524288 .. 524292)  cnt
//   [524352 .. ...   )  list  : ambiguous row indices
#define WS_CNT_OFF   (256 * TILE_B)
#define WS_LIST_OFF  (WS_CNT_OFF + 64)

typedef float f32x4 __attribute__((ext_vector_type(4)));
typedef short s16x8 __attribute__((ext_vector_type(8)));

__device__ __forceinline__ unsigned short f32_to_bf16_rne(float f) {
    unsigned int u = __float_as_uint(f);
    u = (u + 0x7fffu + ((u >> 16) & 1u)) >> 16;
    return (unsigned short)u;
}
__device__ __forceinline__ float bf16_to_f32(unsigned short h) {
    return __uint_as_float(((unsigned int)h) << 16);
}
__device__ __forceinline__ uint32_t umin32(uint32_t a, uint32_t b) { return a < b ? a : b; }
__device__ __forceinline__ uint32_t umax32(uint32_t a, uint32_t b) { return a > b ? a : b; }

// ---------------------------------------------------------------------------
// Kernel 1: pack Y fragments. Per (tile T, lane l): q = l>>4, c = l&15,
// n = T*16 + c.
//   B1[j] = yh[(q&1)*8 + j]                      (k 0..15 and 16..31 = yh)
//   B2: q<2 -> yl[(q&1)*8 + j]; q==2 -> (ysqb_hi, ysqb_lo, 0...); q==3 -> 0
// where ysqb = ||y||^2 + SCORE_BIAS, split bf16. Pairs with screen's
// A1=[ah|al], A2=[ah|1,1,0...] to give score+bias with no epilogue math.
// ---------------------------------------------------------------------------
__global__ void pack_y_kernel(const float* __restrict__ verts,
                              char* __restrict__ yfrag,
                              int* __restrict__ cnt) {
    const int tid = blockIdx.x * blockDim.x + threadIdx.x;
    if (tid == 0) *cnt = 0;
    const int T = tid >> 6;
    const int l = tid & 63;
    if (T >= N_TILES) return;
    const int q = l >> 4;
    const int c = l & 15;
    const int n = T * 16 + c;

    const float* y = verts + (size_t)n * D_DIM;
    float yv[16];
#pragma unroll
    for (int d = 0; d < D_DIM; ++d) yv[d] = y[d];
    float ysb = SCORE_BIAS;
#pragma unroll
    for (int d = 0; d < D_DIM; ++d) ysb = fmaf(yv[d], yv[d], ysb);

    const int half = (q & 1) * 8;
    s16x8 b1, b2;
    const unsigned short ysq_hi = f32_to_bf16_rne(ysb);
    const unsigned short ysq_lo = f32_to_bf16_rne(ysb - bf16_to_f32(ysq_hi));
#pragma unroll
    for (int j = 0; j < 8; ++j) {
        const float v = yv[half + j];
        const unsigned short hh = f32_to_bf16_rne(v);
        b1[j] = (short)hh;
        unsigned short b2v;
        if (q < 2)       b2v = f32_to_bf16_rne(v - bf16_to_f32(hh));  // yl
        else if (q == 2) b2v = (j == 0) ? ysq_hi : ((j == 1) ? ysq_lo : 0);
        else             b2v = 0;
        b2[j] = (short)b2v;
    }
    char* p = yfrag + (size_t)T * TILE_B + l * 16;
    *(s16x8*)p = b1;
    *(s16x8*)(p + 1024) = b2;
}

// ---------------------------------------------------------------------------
// Kernel 2 (MFMA screen): 256 thr = 4 waves, wave = 16 rows, no LDS staging,
// no K-loop barriers. Fragments stream from L2 (512 KB total, shared by all
// blocks) via coalesced dwordx4 loads with 1-pair-ahead prefetch; 8 waves/SIMD
// of TLP hides the rest. Two chained MFMAs from a once-zeroed C quad produce
// score+bias directly (ysq folded into B2/A2) -> zero per-tile acc-init.
// Select: key=(bits&~0xFF)|tile; min_u32=best+argmin, max+min=second.
// ---------------------------------------------------------------------------
__global__ __launch_bounds__(256, 8) void mfma_screen_kernel(
    const float* __restrict__ x_all,    // (M,16)
    const float* __restrict__ colors,   // (N,3)
    const char* __restrict__ yfrag,     // N_TILES x 2048 B
    float* __restrict__ out,            // (M,3)
    int* __restrict__ cnt,
    int* __restrict__ list,
    int list_cap)
{
    __shared__ uint32_t s_red [4 * 256];
    __shared__ uint32_t s_red2[4 * 256];

    const int tid  = threadIdx.x;
    const int wave = tid >> 6;
    const int lane = tid & 63;
    const int q = lane >> 4;
    const int c = lane & 15;
    const int rowBase = blockIdx.x * 64 + wave * 16;

    // --- A fragments. A1 = [ah | al], A2 = [ah | (1,1,0,...)] of a = -2x.
    const float* xr = x_all + (size_t)(rowBase + c) * D_DIM + (q & 1) * 8;
    const float4 xa = *(const float4*)xr;
    const float4 xb = *(const float4*)(xr + 4);
    const float xv[8] = {xa.x, xa.y, xa.z, xa.w, xb.x, xb.y, xb.z, xb.w};
    s16x8 a1, a2;
#pragma unroll
    for (int j = 0; j < 8; ++j) {
        const float a = -2.0f * xv[j];
        const unsigned short hh = f32_to_bf16_rne(a);
        const unsigned short ll = f32_to_bf16_rne(a - bf16_to_f32(hh));
        a1[j] = (short)((q < 2) ? hh : ll);
        unsigned short e = 0;
        if (q == 2 && j < 2) e = 0x3F80;   // bf16 1.0
        a2[j] = (short)((q < 2) ? hh : e);
    }

    const f32x4 zero4 = {0.f, 0.f, 0.f, 0.f};
    uint32_t best[4]   = {0xFFFFFFFFu, 0xFFFFFFFFu, 0xFFFFFFFFu, 0xFFFFFFFFu};
    uint32_t second[4] = {0xFFFFFFFFu, 0xFFFFFFFFu, 0xFFFFFFFFu, 0xFFFFFFFFu};

    const char* base = yfrag + lane * 16;
    s16x8 b1c = *(const s16x8*)(base);
    s16x8 b2c = *(const s16x8*)(base + 1024);
    s16x8 b1n = *(const s16x8*)(base + TILE_B);
    s16x8 b2n = *(const s16x8*)(base + TILE_B + 1024);

#pragma unroll 2
    for (int t = 0; t < N_TILES; ++t) {
        // Prefetch tile t+2 (clamped; last-iter dup loads are unused).
        const int tp = (t + 2 < N_TILES) ? t + 2 : N_TILES - 1;
        const char* pp = base + (size_t)tp * TILE_B;
        const s16x8 p1 = *(const s16x8*)(pp);
        const s16x8 p2 = *(const s16x8*)(pp + 1024);

        f32x4 acc = __builtin_amdgcn_mfma_f32_16x16x32_bf16(a1, b1c, zero4, 0, 0, 0);
        acc = __builtin_amdgcn_mfma_f32_16x16x32_bf16(a2, b2c, acc, 0, 0, 0);
        const uint32_t tcur = (uint32_t)t;
#pragma unroll
        for (int r = 0; r < 4; ++r) {
            const uint32_t kb = (__float_as_uint(acc[r]) & 0xFFFFFF00u) | tcur;
            const uint32_t ob = best[r];
            second[r] = umin32(second[r], umax32(ob, kb));
            best[r]   = umin32(ob, kb);
        }
        b1c = b1n; b2c = b2n;
        b1n = p1;  b2n = p2;
    }

    // --- Cross-c reduce via LDS (keeps keys 8-bit-tile only; c recovered).
#pragma unroll
    for (int r = 0; r < 4; ++r) {
        const int row = q * 4 + r;            // C/D: row = (lane>>4)*4 + reg
        s_red [wave * 256 + row * 16 + c] = best[r];
        s_red2[wave * 256 + row * 16 + c] = second[r];
    }
    __syncthreads();

    if (lane < 16) {
        const int row = lane;
        uint32_t b1 = 0xFFFFFFFFu, b2 = 0xFFFFFFFFu, smin = 0xFFFFFFFFu;
        int cwin = 0;
#pragma unroll
        for (int cc = 0; cc < 16; ++cc) {
            const uint32_t k  = s_red [wave * 256 + row * 16 + cc];
            const uint32_t s2 = s_red2[wave * 256 + row * 16 + cc];
            smin = umin32(smin, s2);
            cwin = (k < b1) ? cc : cwin;      // strict <: earliest c on ties
            b2 = umin32(b2, umax32(b1, k));   // 2nd-min of bests
            b1 = umin32(b1, k);
        }
        const uint32_t secondAll = umin32(smin, b2);
        const float s1 = __uint_as_float(b1 & 0xFFFFFF00u);
        const float s2 = __uint_as_float(secondAll & 0xFFFFFF00u);
        const int n = (int)(b1 & 0xFFu) * 16 + cwin;
        const int m = rowBase + row;

        bool amb = (s2 - s1 <= TIE_EPS);
        if (amb) {
            const int pos = atomicAdd(cnt, 1);
            if (pos < list_cap) list[pos] = m;
            else amb = false;                 // overflow: keep screened winner
        }
        if (!amb) {
            const float* cc2 = colors + (size_t)n * 3;
            float* o = out + (size_t)m * 3;
            o[0] = cc2[0];
            o[1] = cc2[1];
            o[2] = cc2[2];
        }
    }
}

// ---------------------------------------------------------------------------
// Kernel 3 (rescan): one wave per ambiguous row, fp64 exact (= f64 numpy ref);
// 8192 waves of TLP; lexicographic (s, idx) butterfly = first-index argmin.
// ---------------------------------------------------------------------------
__global__ __launch_bounds__(256) void rescan_kernel(
    const float* __restrict__ x_all,
    const float* __restrict__ colors,
    const float* __restrict__ verts,
    const int* __restrict__ cnt,
    const int* __restrict__ list,
    int list_cap,
    float* __restrict__ out)
{
    const int wavesPerBlock = blockDim.x >> 6;
    const int wid  = blockIdx.x * wavesPerBlock + (threadIdx.x >> 6);
    const int lane = threadIdx.x & 63;
    const int nWaves = gridDim.x * wavesPerBlock;

    int ccount = *cnt;
    if (ccount > list_cap) ccount = list_cap;

    for (int rr = wid; rr < ccount; rr += nWaves) {
        const int m = list[rr];
        double bx[D_DIM];
#pragma unroll
        for (int d = 0; d < D_DIM; ++d)
            bx[d] = (double)x_all[(size_t)m * D_DIM + d];

        double best = INFINITY;
        int bi = 0x7fffffff;
#pragma unroll 2
        for (int n = lane; n < N_VERTS; n += 64) {
            const float* y = verts + (size_t)n * D_DIM;
            double dot = 0.0, ys = 0.0;
#pragma unroll
            for (int d = 0; d < D_DIM; ++d) {
                const double yd = (double)y[d];
                dot = fma(bx[d], yd, dot);
                ys  = fma(yd, yd, ys);
            }
            const double s = ys - 2.0 * dot;
            if (s < best || (s == best && n < bi)) { best = s; bi = n; }
        }
#pragma unroll
        for (int off = 32; off > 0; off >>= 1) {
            const double ob = __shfl_xor(best, off, 64);
            const int    oi = __shfl_xor(bi, off, 64);
            if (ob < best || (ob == best && oi < bi)) { best = ob; bi = oi; }
        }
        if (lane == 0) {
            const float* cc = colors + (size_t)bi * 3;
            float* o = out + (size_t)m * 3;
            o[0] = cc[0];
            o[1] = cc[1];
            o[2] = cc[2];
        }
    }
}

// ---------------------------------------------------------------------------
extern "C" void kernel_launch(void* const* d_in, const int* in_sizes, int n_in,
                              void* d_out, int out_size, void* d_ws, size_t ws_size,
                              hipStream_t stream) {
    const float* cse_embedding       = (const float*)d_in[0]; // (M,16)
    const float* verts_colors        = (const float*)d_in[1]; // (N,3)
    const float* verts_cse_embedding = (const float*)d_in[2]; // (N,16)
    float* out = (float*)d_out;                               // (M,3)

    char* ws = (char*)d_ws;
    char* yfrag = ws;
    int*  cnt   = (int*)(ws + WS_CNT_OFF);
    int*  list  = (int*)(ws + WS_LIST_OFF);
    int list_cap = (int)((ws_size > WS_LIST_OFF)
                         ? ((ws_size - WS_LIST_OFF) / sizeof(int)) : 0);
    if (list_cap > M_ROWS) list_cap = M_ROWS;

    pack_y_kernel<<<(N_TILES * 64 + 255) / 256, 256, 0, stream>>>(
        verts_cse_embedding, yfrag, cnt);

    mfma_screen_kernel<<<M_ROWS / 64, 256, 0, stream>>>(
        cse_embedding, verts_colors, yfrag, out, cnt, list, list_cap);

    rescan_kernel<<<2048, 256, 0, stream>>>(
        cse_embedding, verts_colors, verts_cse_embedding, cnt, list,
        list_cap, out);
}